// Round 10
// baseline (47.222 us; speedup 1.0000x reference)
//
#include <hip/hip_runtime.h>
#include <math.h>

#define BATCH   64
#define IN_DIM  8192
#define OUT_DIM 2048
#define BRANCH  4
#define CHUNK   2048
#define KT      128    // k per LDS tile
#define NTILE   16     // CHUNK / KT

typedef __attribute__((ext_vector_type(8))) short short8;   // 8 x bf16 (4 VGPR) MFMA operand
typedef __attribute__((ext_vector_type(4))) short short4v;  // 8-byte packed bf16x4
typedef __attribute__((ext_vector_type(4))) float f32x4;

__device__ __forceinline__ float sigmoidf_(float x) {
    return 1.0f / (1.0f + expf(-x));
}

// round-to-nearest-even fp32 -> bf16 bit pattern (low 16 bits of result)
__device__ __forceinline__ unsigned rne_bf16(float f) {
    unsigned u = __float_as_uint(f);
    return (u + 0x7fffu + ((u >> 16) & 1u)) >> 16;
}

// Barrier that does NOT drain vmcnt: LDS-visibility only (R7-verified safe).
#define LBAR()                                                   \
    do {                                                         \
        asm volatile("s_waitcnt lgkmcnt(0)" ::: "memory");       \
        __builtin_amdgcn_s_barrier();                            \
        asm volatile("" ::: "memory");                           \
    } while (0)

// ---------------------------------------------------------------------------
// prep: X fp32 [64][8192] -> A-fragment-layout bf16 hi/lo streams (verified R2-R7).
// frag element index = (j*4 + strip)*4096 + kk*64 + lane ;
// lane l holds X[n = strip*16 + (l&15)][j*2048 + kk*32 + (l>>4)*8 + e], e=0..7
__global__ __launch_bounds__(256) void prep_x(const float* __restrict__ X,
                                              short8* __restrict__ Xfh,
                                              short8* __restrict__ Xfl) {
    const int gid = blockIdx.x * 256 + threadIdx.x;   // 65536 frag-lanes
    const int l  = gid & 63;
    const int kk = (gid >> 6) & 63;
    const int s  = (gid >> 12) & 3;
    const int j  = gid >> 14;
    const int n  = s * 16 + (l & 15);
    const int k0 = kk * 32 + ((l >> 4) << 3);
    const float* p = X + (size_t)n * IN_DIM + j * CHUNK + k0;
    const f32x4 a = *(const f32x4*)p;
    const f32x4 c = *(const f32x4*)(p + 4);
    float v[8] = {a[0], a[1], a[2], a[3], c[0], c[1], c[2], c[3]};
    short8 h, lo;
#pragma unroll
    for (int e = 0; e < 8; ++e) {
        unsigned hb = rne_bf16(v[e]);
        float fh = __uint_as_float(hb << 16);
        unsigned lb = rne_bf16(v[e] - fh);
        h[e]  = (short)hb;
        lo[e] = (short)lb;
    }
    Xfh[gid] = h;
    Xfl[gid] = lo;
}

// ---------------------------------------------------------------------------
// stage fp32 W regs -> split bf16 hi/lo in swizzled LDS.
// 64 rows x 256B; swizzle key = ((row>>2)&15)<<4  (== o_l<<4 on the read side).
__device__ __forceinline__ void stage_store(char* Wh, char* Wl, const f32x4* wr,
                                            int wbyte0, int swz, int kq) {
#pragma unroll
    for (int i = 0; i < 4; ++i) {
        unsigned hb[4], lb[4];
#pragma unroll
        for (int e = 0; e < 4; ++e) {
            float f = wr[i][e];
            unsigned h = rne_bf16(f);
            float fh = __uint_as_float(h << 16);
            unsigned l = rne_bf16(f - fh);
            hb[e] = h; lb[e] = l;
        }
        short4v vh = { (short)hb[0], (short)hb[1], (short)hb[2], (short)hb[3] };
        short4v vl = { (short)lb[0], (short)lb[1], (short)lb[2], (short)lb[3] };
        const int kb   = (kq << 5) + (i << 3);
        const int byte = wbyte0 + (kb ^ swz);
        *(short4v*)(Wh + byte) = vh;
        *(short4v*)(Wl + byte) = vl;
    }
}

// ---------------------------------------------------------------------------
// Fused block-diagonal GEMM + dendritic decay + LIF + spike.
// grid: 128 blocks = o-tiles of 16 outputs (all 4 branches, all 64 batches, full K).
// block: 512 thr = 8 waves = (n-half 0..1) x (branch j 0..3).
// Wave (nsp,j): 32 batches x 16 outputs, K=2048 of branch j; B-frags shared
// across its two 16-n strips. W read once from HBM (67 MB total).
// Epilogue: LDS branch-reduction + per-branch beta + LIF, direct out write.
__global__ __launch_bounds__(512) void dend_fused(
    const short8* __restrict__ Xfh,
    const short8* __restrict__ Xfl,
    const float*  __restrict__ W,
    const float*  __restrict__ mem,
    const float*  __restrict__ spike,
    const float*  __restrict__ d_input,
    const float*  __restrict__ v_th,
    const float*  __restrict__ bias,
    const float*  __restrict__ tau_m,
    const float*  __restrict__ tau_n,
    float* __restrict__ out)
{
    __shared__ __align__(16) char WhL[2][64 * 256];   // 16 KB per buffer
    __shared__ __align__(16) char WlL[2][64 * 256];

    const int t    = threadIdx.x;
    const int bid  = blockIdx.x;       // outputs bid*16 .. bid*16+16
    const int lane = t & 63;
    const int wv   = t >> 6;           // 0..7
    const int nsp  = wv >> 2;          // n-half
    const int j    = wv & 3;           // branch

    // W staging: 8 threads per local row (64 rows), 16 fp32 each.
    // global W row = bid*64 + ri ; its k-cols come from chunk (ri&3).
    const int ri  = t >> 3;            // 0..63
    const int kq  = t & 7;
    const float* wsrc = W + (size_t)(bid * 64 + ri) * IN_DIM
                          + (ri & 3) * CHUNK + kq * 16;
    const int wbyte0 = ri << 8;
    const int swz    = ((ri >> 2) & 15) << 4;

    // B-frag read addressing: local row lr = o_l*4 + j ; key (lr>>2)&15 == o_l.
    const int o_l  = lane & 15;
    const int q    = lane >> 4;        // 0..3
    const int brow = (o_l * 4 + j) << 8;
    const int bswz = o_l << 4;
    const int kgrp = q << 4;

    // A-frag streams for strips s0 = nsp*2, s0+1 (full K: kk = 0..63)
    const int s0 = nsp * 2;
    const short8* pAh0 = Xfh + (j * 4 + s0) * 4096 + lane;
    const short8* pAl0 = Xfl + (j * 4 + s0) * 4096 + lane;
    const short8* pAh1 = pAh0 + 4096;
    const short8* pAl1 = pAl0 + 4096;

    f32x4 acc0 = {0.f, 0.f, 0.f, 0.f};   // strip s0
    f32x4 acc1 = {0.f, 0.f, 0.f, 0.f};   // strip s0+1

    f32x4  wr[4];
    // two A half-tile slots (2 kk each): X = even halves, Y = odd halves
    short8 AXh0[2], AXl0[2], AXh1[2], AXl1[2];
    short8 AYh0[2], AYl0[2], AYh1[2], AYl1[2];

#define LOADA(P, base)                                         \
  if ((base) < 64) {                                           \
    _Pragma("unroll")                                          \
    for (int u = 0; u < 2; ++u) {                              \
        A##P##h0[u] = pAh0[((base) + u) * 64];                 \
        A##P##l0[u] = pAl0[((base) + u) * 64];                 \
        A##P##h1[u] = pAh1[((base) + u) * 64];                 \
        A##P##l1[u] = pAl1[((base) + u) * 64];                 \
    }                                                          \
  }

#define CONSUME(P, kt, stbase)                                                        \
  { _Pragma("unroll")                                                                 \
    for (int u = 0; u < 2; ++u) {                                                     \
        const int off = ((((stbase) + u) << 6) + kgrp) ^ bswz;                        \
        const short8 bh = *(const short8*)(&WhL[(kt) & 1][brow + off]);               \
        const short8 bl = *(const short8*)(&WlL[(kt) & 1][brow + off]);               \
        acc0 = __builtin_amdgcn_mfma_f32_16x16x32_bf16(A##P##h0[u], bh, acc0, 0,0,0); \
        acc1 = __builtin_amdgcn_mfma_f32_16x16x32_bf16(A##P##h1[u], bh, acc1, 0,0,0); \
        acc0 = __builtin_amdgcn_mfma_f32_16x16x32_bf16(A##P##l0[u], bh, acc0, 0,0,0); \
        acc1 = __builtin_amdgcn_mfma_f32_16x16x32_bf16(A##P##l1[u], bh, acc1, 0,0,0); \
        acc0 = __builtin_amdgcn_mfma_f32_16x16x32_bf16(A##P##h0[u], bl, acc0, 0,0,0); \
        acc1 = __builtin_amdgcn_mfma_f32_16x16x32_bf16(A##P##h1[u], bl, acc1, 0,0,0); \
    } }

    // ---- prologue: W tiles 0,1 ; A half 0 (kk 0,1) ----
#pragma unroll
    for (int i = 0; i < 4; ++i)
        wr[i] = *(const f32x4*)(wsrc + i * 4);
    stage_store(&WhL[0][0], &WlL[0][0], wr, wbyte0, swz, kq);
#pragma unroll
    for (int i = 0; i < 4; ++i)
        wr[i] = *(const f32x4*)(wsrc + KT + i * 4);
    LOADA(X, 0)
    LBAR();

#pragma unroll 1
    for (int kt = 0; kt < NTILE; ++kt) {
        if (kt + 1 < NTILE)
            stage_store(&WhL[(kt + 1) & 1][0], &WlL[(kt + 1) & 1][0],
                        wr, wbyte0, swz, kq);
        if (kt + 2 < NTILE) {
#pragma unroll
            for (int i = 0; i < 4; ++i)
                wr[i] = *(const f32x4*)(wsrc + (kt + 2) * KT + i * 4);
        }
        LOADA(Y, kt * 4 + 2)     // odd half of this tile
        CONSUME(X, kt, 0)        // kk = 4kt, 4kt+1
        LOADA(X, kt * 4 + 4)     // even half of NEXT tile
        CONSUME(Y, kt, 2)        // kk = 4kt+2, 4kt+3
        LBAR();
    }
#undef LOADA
#undef CONSUME

    // ---- epilogue: branch-reduce in LDS (alias onto W buffers), then LIF ----
    float* Ysum = (float*)&WhL[0][0];          // [4 j][64 n][17] = 17.4 KB
    {
#pragma unroll
        for (int r = 0; r < 4; ++r) {
            const int n0 = s0 * 16 + q * 4 + r;         // strip s0
            Ysum[(j * 64 + n0)      * 17 + o_l] = acc0[r];
            Ysum[(j * 64 + n0 + 16) * 17 + o_l] = acc1[r];
        }
    }
    __syncthreads();

#pragma unroll
    for (int p = 0; p < 2; ++p) {
        const int e  = t + p * 512;            // 0..1023 = 64 n x 16 oo
        const int oo = e & 15;
        const int n  = e >> 4;
        const int og = bid * 16 + oo;          // global output
        const int idx = n * OUT_DIM + og;

        const float y0 = Ysum[(0 * 64 + n) * 17 + oo];
        const float y1 = Ysum[(1 * 64 + n) * 17 + oo];
        const float y2 = Ysum[(2 * 64 + n) * 17 + oo];
        const float y3 = Ysum[(3 * 64 + n) * 17 + oo];

        const float4 tn = ((const float4*)tau_n)[og];
        const float4 bb = ((const float4*)bias)[og];
        const float4 di = ((const float4*)d_input)[idx];

        float l = 0.0f;
        { const float bt = sigmoidf_(tn.x); l += bt * di.x + (1.0f - bt) * (y0 + bb.x); }
        { const float bt = sigmoidf_(tn.y); l += bt * di.y + (1.0f - bt) * (y1 + bb.y); }
        { const float bt = sigmoidf_(tn.z); l += bt * di.z + (1.0f - bt) * (y2 + bb.z); }
        { const float bt = sigmoidf_(tn.w); l += bt * di.w + (1.0f - bt) * (y3 + bb.w); }

        const float alpha = sigmoidf_(tau_m[og]);
        const float vt    = v_th[idx];
        const float m     = mem[idx] * alpha + (1.0f - alpha) * l - vt * spike[idx];

        out[idx] = m;
        out[BATCH * OUT_DIM + idx] = (m - vt) > 0.0f ? 1.0f : 0.0f;
    }
}

extern "C" void kernel_launch(void* const* d_in, const int* in_sizes, int n_in,
                              void* d_out, int out_size, void* d_ws, size_t ws_size,
                              hipStream_t stream) {
    const float* X     = (const float*)d_in[0];
    const float* mem   = (const float*)d_in[1];
    const float* spike = (const float*)d_in[2];
    const float* dinp  = (const float*)d_in[3];
    const float* vth   = (const float*)d_in[4];
    const float* W     = (const float*)d_in[5];
    const float* b     = (const float*)d_in[6];
    const float* tm    = (const float*)d_in[7];
    const float* tn    = (const float*)d_in[8];
    float* out = (float*)d_out;

    // workspace: Xfh (1 MB) | Xfl (1 MB)
    short8* Xfh = (short8*)d_ws;
    short8* Xfl = (short8*)((char*)d_ws + (1u << 20));

    prep_x<<<256, 256, 0, stream>>>(X, Xfh, Xfl);
    dend_fused<<<128, 512, 0, stream>>>(Xfh, Xfl, W, mem, spike, dinp, vth,
                                        b, tm, tn, out);
}